// Round 1
// baseline (612.787 us; speedup 1.0000x reference)
//
#include <hip/hip_runtime.h>

// SpaAggregator: out[b] = (mean_k id2feat[idx[b,k]]) @ W + bias
// B=16384, K=32, N=1e6, F=128, E=128. float32 in/out, int32 indices.
//
// mean commutes with the linear map: gather-average first, then a tiny GEMM.
// The gather (268 MB of random 512B-row reads) is CONCURRENCY-bound, not
// BW-bound: the previous version staged W (64 KB) in LDS, capping occupancy
// at 2 blocks/CU (25%). W is block-invariant and L1/L2-resident, so phase 3
// now reads it straight from global; LDS drops to ~5.3 KB and the grid grows
// to 2048 blocks so the CU can hold ~6-8 blocks (24-32 waves) and keep 3-4x
// more row fetches in flight.
//
// Block = 256 threads handles 8 batch rows:
//   phase 1: stage 256 neighbor indices -> LDS (one pass, padded pitch)
//   phase 2: gather-average; 32 lanes x 16B cover one 512B table row
//            contiguously; 32 neighbors deep, unroll 8 (8 loads in flight)
//   phase 3: per-thread 1x4 output tile; A-row broadcast from LDS, W row
//            (512B, wave-contiguous) from L1/L2, fp32 store.

#define BATCH 16384
#define KNB   32
#define FDIM  128
#define EDIM  128
#define ROWS_PER_BLOCK 8
#define IDX_PITCH 33   // pad: lb groups land on different banks
#define A_PITCH  132   // pad: phase-3 broadcast reads differ across lb

__global__ __launch_bounds__(256, 6)
void spa_agg_kernel(const float* __restrict__ id2feat,
                    const float* __restrict__ weight,
                    const float* __restrict__ bias,
                    const int* __restrict__ neigh_idx,
                    float* __restrict__ out) {
    __shared__ float sA[ROWS_PER_BLOCK * A_PITCH];     // ~4.2 KB
    __shared__ int   sIdx[ROWS_PER_BLOCK * IDX_PITCH]; // ~1.1 KB

    const int tid = threadIdx.x;
    const int lb  = tid >> 5;   // 0..7  : local batch row
    const int lr  = tid & 31;   // 0..31 : 4-wide feature/embed chunk
    const int b0  = blockIdx.x * ROWS_PER_BLOCK;

    // ---- phase 1: stage neighbor indices (exactly 256 = blockDim) ----
    {
        sIdx[lb * IDX_PITCH + lr] = neigh_idx[b0 * KNB + tid];
    }
    __syncthreads();

    // ---- phase 2: gather + average ----
    // thread (lb, lr) accumulates features [lr*4, lr*4+4) of local row lb.
    // 32 consecutive lanes read one 512B table row contiguously (16B/lane).
    {
        float a0 = 0.f, a1 = 0.f, a2 = 0.f, a3 = 0.f;
        const int* ip = &sIdx[lb * IDX_PITCH];
        const float* gbase = id2feat + lr * 4;
        #pragma unroll 8
        for (int k = 0; k < KNB; ++k) {
            const int row = ip[k];
            const float4 r0 = *(const float4*)(gbase + (size_t)row * FDIM);
            a0 += r0.x; a1 += r0.y; a2 += r0.z; a3 += r0.w;
        }
        *(float4*)&sA[lb * A_PITCH + lr * 4] =
            make_float4(a0 * (1.f / 32.f), a1 * (1.f / 32.f),
                        a2 * (1.f / 32.f), a3 * (1.f / 32.f));
    }
    __syncthreads();

    // ---- phase 3: out[b0+lb][e0..e0+4) = sA[lb] . W[:, e0..e0+4) + bias ----
    // W row f is 512B and wave-contiguous across lanes; it is re-read by all
    // blocks and stays L1/L2-resident (64 KB total).
    {
        const int e0 = lr * 4;
        float4 acc = *(const float4*)(bias + e0);
        const float* arow = &sA[lb * A_PITCH];
        const float* wp = weight + e0;
        #pragma unroll 8
        for (int f = 0; f < FDIM; ++f) {
            const float a  = arow[f];                          // LDS broadcast
            const float4 w = *(const float4*)(wp + (size_t)f * EDIM);
            acc.x += a * w.x; acc.y += a * w.y;
            acc.z += a * w.z; acc.w += a * w.w;
        }
        *(float4*)(out + (size_t)(b0 + lb) * EDIM + e0) = acc;
    }
}

extern "C" void kernel_launch(void* const* d_in, const int* in_sizes, int n_in,
                              void* d_out, int out_size, void* d_ws, size_t ws_size,
                              hipStream_t stream) {
    const float* id2feat = (const float*)d_in[0];  // [N, F] fp32
    const float* weight  = (const float*)d_in[1];  // [F, E] fp32
    const float* bias    = (const float*)d_in[2];  // [E]    fp32
    const int*   neigh   = (const int*)d_in[3];    // [B, K] int32
    float*       outp    = (float*)d_out;          // [B, E] fp32

    dim3 grid(BATCH / ROWS_PER_BLOCK);  // 2048
    dim3 block(256);
    spa_agg_kernel<<<grid, block, 0, stream>>>(id2feat, weight, bias, neigh, outp);
}